// Round 6
// baseline (2312.220 us; speedup 1.0000x reference)
//
#include <hip/hip_runtime.h>
#include <hip/hip_bf16.h>
#include <math.h>

#define D_MODEL 768
#define N_LAYER 2
#define VOCAB   50257
#define D_STATE 16
#define D_CONV  4
#define D_INNER 1536
#define DT_RANK 48
#define NB 2
#define NL 1024
#define NTOK (NB*NL)   // 2048
#define XPROJ_OUT (DT_RANK + 2*D_STATE)  // 80
#define CH 16          // scan chunks
#define CHL (NL/CH)    // 64 steps per chunk
#define HCHK 12800     // head vocab-chunk rows (multiple of 128)

typedef __attribute__((ext_vector_type(8))) short bf16x8;
typedef __attribute__((ext_vector_type(8))) unsigned short u16x8;
typedef __attribute__((ext_vector_type(4))) float f32x4;

// fp32 -> bf16 hi + bf16 lo (hi truncated, lo = RN(residual)); x ≈ hi+lo, err ~2^-16|x|
__device__ __forceinline__ void cvt_hl(float f, unsigned short& h, unsigned short& l) {
    unsigned bi = __float_as_uint(f);
    unsigned hb = bi & 0xFFFF0000u;
    h = (unsigned short)(hb >> 16);
    float r = f - __uint_as_float(hb);
    l = (unsigned short)((__float_as_uint(r) + 0x8000u) >> 16);
}

// ---------------- embedding gather ----------------
__global__ void k_embed(const int* __restrict__ ids, const float* __restrict__ emb,
                        float* __restrict__ x) {
    int row = blockIdx.x;
    int id  = ids[row];
    const float4* src = (const float4*)(emb + (size_t)id * D_MODEL);
    float4*       dst = (float4*)(x + (size_t)row * D_MODEL);
    dst[threadIdx.x] = src[threadIdx.x];   // 192 threads * float4 = 768 floats
}

// ---------------- split pass: fp32 array -> hi/lo bf16 arrays ----------------
__global__ void k_split(const float* __restrict__ in, unsigned short* __restrict__ hi,
                        unsigned short* __restrict__ lo, int n8) {   // n8 = n/8
    int i = blockIdx.x * 256 + threadIdx.x;
    if (i >= n8) return;
    const float4* p = (const float4*)in + 2*(size_t)i;
    float4 f0 = p[0], f1 = p[1];
    float v[8] = {f0.x,f0.y,f0.z,f0.w,f1.x,f1.y,f1.z,f1.w};
    u16x8 h, l;
    #pragma unroll
    for (int j = 0; j < 8; j++) {
        unsigned short hh, ll;
        cvt_hl(v[j], hh, ll);
        h[j] = hh; l[j] = ll;
    }
    *((u16x8*)hi + i) = h;
    *((u16x8*)lo + i) = l;
}

#define LDST 40   // LDS row stride in ushort (32 payload + 8 pad = 80B rows)

// ---------------- MFMA GEMM on pre-split operands -------------------------
// C[M,N] = (Ah+Al)[M,K] * (Bh+Bl)[N,K]^T via 3 MFMAs (hh+lh+hl).
// 128x128 tile, BK=32, 256 threads = 4 waves tiled 2x2; wave (wm,wn) owns the
// 64x64 sub-tile at (64*wm, 64*wn). Per k-step per wave: 16 ds_read_b128
// (~192 cyc) vs 48 MFMA (~233 cyc) -> MFMA-bound. M%128==0, K%32==0. N tail guarded.
__global__ __launch_bounds__(256)
void k_gemm_pair(const unsigned short* __restrict__ Ah, const unsigned short* __restrict__ Al,
                 const unsigned short* __restrict__ Bh, const unsigned short* __restrict__ Bl,
                 float* __restrict__ C, int M, int N, int K, int ldc) {
    __shared__ unsigned short Ah_s[128*LDST];
    __shared__ unsigned short Al_s[128*LDST];
    __shared__ unsigned short Bh_s[128*LDST];
    __shared__ unsigned short Bl_s[128*LDST];

    const int tid  = threadIdx.x;
    const int lane = tid & 63;
    const int wv   = tid >> 6;
    const int wm   = wv >> 1;            // 0..1
    const int wn   = wv & 1;             // 0..1
    const int bm = blockIdx.x * 128;
    const int bn = blockIdx.y * 128;

    const int srow  = tid >> 1;          // 0..127
    const int skoff = (tid & 1) * 16;    // 0 or 16
    const size_t abase0 = (size_t)(bm + srow) * K + skoff;
    const int brow  = bn + srow;
    const bool bok  = brow < N;
    const size_t bbase0 = (size_t)(bok ? brow : 0) * K + skoff;

    f32x4 acc[4][4];
    #pragma unroll
    for (int m = 0; m < 4; m++)
        #pragma unroll
        for (int n = 0; n < 4; n++)
            acc[m][n] = (f32x4){0.f, 0.f, 0.f, 0.f};

    const u16x8 zero8 = {};
    u16x8 rah[2], ral[2], rbh[2], rbl[2];
    #pragma unroll
    for (int q = 0; q < 2; q++) {
        rah[q] = *(const u16x8*)(Ah + abase0 + 8*q);
        ral[q] = *(const u16x8*)(Al + abase0 + 8*q);
        rbh[q] = bok ? *(const u16x8*)(Bh + bbase0 + 8*q) : zero8;
        rbl[q] = bok ? *(const u16x8*)(Bl + bbase0 + 8*q) : zero8;
    }

    const int sbase = srow*LDST + skoff;
    const int lane15 = lane & 15;
    const int kb = (lane >> 4) * 8;                 // k-offset within 32-k tile
    const int ar0 = (wm*64 + lane15)*LDST + kb;     // A frag base (m adds 16*LDST)
    const int br0 = (wn*64 + lane15)*LDST + kb;     // B frag base (n adds 16*LDST)
    const int nk = K / 32;

    for (int t = 0; t < nk; t++) {
        __syncthreads();   // previous tile's reads done
        #pragma unroll
        for (int q = 0; q < 2; q++) {
            *(u16x8*)&Ah_s[sbase + 8*q] = rah[q];
            *(u16x8*)&Al_s[sbase + 8*q] = ral[q];
            *(u16x8*)&Bh_s[sbase + 8*q] = rbh[q];
            *(u16x8*)&Bl_s[sbase + 8*q] = rbl[q];
        }
        __syncthreads();   // tile ready
        if (t + 1 < nk) {  // prefetch next k-step under this tile's MFMAs
            size_t ab = abase0 + (size_t)(t+1)*32;
            size_t bb = bbase0 + (size_t)(t+1)*32;
            #pragma unroll
            for (int q = 0; q < 2; q++) {
                rah[q] = *(const u16x8*)(Ah + ab + 8*q);
                ral[q] = *(const u16x8*)(Al + ab + 8*q);
                rbh[q] = bok ? *(const u16x8*)(Bh + bb + 8*q) : zero8;
                rbl[q] = bok ? *(const u16x8*)(Bl + bb + 8*q) : zero8;
            }
        }
        bf16x8 ah[4], al[4];
        #pragma unroll
        for (int m = 0; m < 4; m++) {
            ah[m] = *(const bf16x8*)&Ah_s[ar0 + m*16*LDST];
            al[m] = *(const bf16x8*)&Al_s[ar0 + m*16*LDST];
        }
        #pragma unroll
        for (int n = 0; n < 4; n++) {
            bf16x8 vbh = *(const bf16x8*)&Bh_s[br0 + n*16*LDST];
            bf16x8 vbl = *(const bf16x8*)&Bl_s[br0 + n*16*LDST];
            #pragma unroll
            for (int m = 0; m < 4; m++) {
                acc[m][n] = __builtin_amdgcn_mfma_f32_16x16x32_bf16(ah[m], vbh, acc[m][n], 0, 0, 0);
                acc[m][n] = __builtin_amdgcn_mfma_f32_16x16x32_bf16(al[m], vbh, acc[m][n], 0, 0, 0);
                acc[m][n] = __builtin_amdgcn_mfma_f32_16x16x32_bf16(ah[m], vbl, acc[m][n], 0, 0, 0);
            }
        }
    }

    // C/D layout: col = lane&15, row = (lane>>4)*4 + reg  [m89]
    const int rbase = bm + wm*64 + (lane >> 4) * 4;
    #pragma unroll
    for (int n = 0; n < 4; n++) {
        const int col = bn + wn*64 + n*16 + lane15;
        if (col < N) {
            #pragma unroll
            for (int m = 0; m < 4; m++)
                #pragma unroll
                for (int r = 0; r < 4; r++)
                    C[(size_t)(rbase + m*16 + r) * ldc + col] = acc[m][n][r];
        }
    }
}

// ---------------- fallback: split-bf16 GEMM with in-kernel conversion -------
__global__ __launch_bounds__(256)
void k_gemm_split(const float* __restrict__ A, const float* __restrict__ B,
                  float* __restrict__ C, int M, int N, int K,
                  int lda, int ldb, int ldc) {
    __shared__ unsigned short Ah_s[128*LDST];
    __shared__ unsigned short Al_s[128*LDST];
    __shared__ unsigned short Bh_s[128*LDST];
    __shared__ unsigned short Bl_s[128*LDST];

    const int tid  = threadIdx.x;
    const int lane = tid & 63;
    const int wv   = tid >> 6;
    const int wm   = wv >> 1;
    const int wn   = wv & 1;
    const int bm = blockIdx.x * 128;
    const int bn = blockIdx.y * 128;

    const int srow  = tid >> 1;
    const int skoff = (tid & 1) * 16;
    const float* Ap = A + (size_t)(bm + srow) * lda + skoff;
    const int brow  = bn + srow;
    const bool bok  = brow < N;
    const float* Bp = B + (size_t)(bok ? brow : 0) * ldb + skoff;

    f32x4 acc[4][4];
    #pragma unroll
    for (int m = 0; m < 4; m++)
        #pragma unroll
        for (int n = 0; n < 4; n++)
            acc[m][n] = (f32x4){0.f, 0.f, 0.f, 0.f};

    float4 ra[4], rb[4];
    #pragma unroll
    for (int q = 0; q < 4; q++) {
        ra[q] = *(const float4*)(Ap + 4*q);
        rb[q] = bok ? *(const float4*)(Bp + 4*q) : make_float4(0.f,0.f,0.f,0.f);
    }

    const int sbase = srow*LDST + skoff;
    const int lane15 = lane & 15;
    const int kb = (lane >> 4) * 8;
    const int ar0 = (wm*64 + lane15)*LDST + kb;
    const int br0 = (wn*64 + lane15)*LDST + kb;
    const int nk = K / 32;

    for (int t = 0; t < nk; t++) {
        __syncthreads();
        #pragma unroll
        for (int q = 0; q < 4; q++) {
            ushort4 h, l;
            cvt_hl(ra[q].x, h.x, l.x); cvt_hl(ra[q].y, h.y, l.y);
            cvt_hl(ra[q].z, h.z, l.z); cvt_hl(ra[q].w, h.w, l.w);
            *(ushort4*)&Ah_s[sbase + 4*q] = h;
            *(ushort4*)&Al_s[sbase + 4*q] = l;
            cvt_hl(rb[q].x, h.x, l.x); cvt_hl(rb[q].y, h.y, l.y);
            cvt_hl(rb[q].z, h.z, l.z); cvt_hl(rb[q].w, h.w, l.w);
            *(ushort4*)&Bh_s[sbase + 4*q] = h;
            *(ushort4*)&Bl_s[sbase + 4*q] = l;
        }
        __syncthreads();
        if (t + 1 < nk) {
            Ap += 32; Bp += 32;
            #pragma unroll
            for (int q = 0; q < 4; q++) {
                ra[q] = *(const float4*)(Ap + 4*q);
                rb[q] = bok ? *(const float4*)(Bp + 4*q) : make_float4(0.f,0.f,0.f,0.f);
            }
        }
        bf16x8 ah[4], al[4];
        #pragma unroll
        for (int m = 0; m < 4; m++) {
            ah[m] = *(const bf16x8*)&Ah_s[ar0 + m*16*LDST];
            al[m] = *(const bf16x8*)&Al_s[ar0 + m*16*LDST];
        }
        #pragma unroll
        for (int n = 0; n < 4; n++) {
            bf16x8 vbh = *(const bf16x8*)&Bh_s[br0 + n*16*LDST];
            bf16x8 vbl = *(const bf16x8*)&Bl_s[br0 + n*16*LDST];
            #pragma unroll
            for (int m = 0; m < 4; m++) {
                acc[m][n] = __builtin_amdgcn_mfma_f32_16x16x32_bf16(ah[m], vbh, acc[m][n], 0, 0, 0);
                acc[m][n] = __builtin_amdgcn_mfma_f32_16x16x32_bf16(al[m], vbh, acc[m][n], 0, 0, 0);
                acc[m][n] = __builtin_amdgcn_mfma_f32_16x16x32_bf16(ah[m], vbl, acc[m][n], 0, 0, 0);
            }
        }
    }

    const int rbase = bm + wm*64 + (lane >> 4) * 4;
    #pragma unroll
    for (int n = 0; n < 4; n++) {
        const int col = bn + wn*64 + n*16 + lane15;
        if (col < N) {
            #pragma unroll
            for (int m = 0; m < 4; m++)
                #pragma unroll
                for (int r = 0; r < 4; r++)
                    C[(size_t)(rbase + m*16 + r) * ldc + col] = acc[m][n][r];
        }
    }
}

// ---------------- generic fp32 NT GEMM (small shapes: x_proj, dt) ----------
template<int EPI>
__global__ __launch_bounds__(256)
void k_gemm_nt(const float* __restrict__ A, const float* __restrict__ B,
               const float* __restrict__ bias, float* __restrict__ C,
               int M, int N, int K, int lda, int ldb, int ldc) {
    __shared__ float As[16][68];
    __shared__ float Bs[16][68];
    const int tid = threadIdx.x;
    const int tx = tid & 15;
    const int ty = tid >> 4;
    const int lr = tid >> 2;
    const int lk = (tid & 3) << 2;
    const int bm = blockIdx.x * 64;
    const int bn = blockIdx.y * 64;

    const int rowA = bm + lr;
    const int rowB = bn + lr;
    const bool bvalid = (rowB < N);

    float acc[4][4] = {};

    for (int k0 = 0; k0 < K; k0 += 16) {
        float4 av = *(const float4*)(A + (size_t)rowA * lda + k0 + lk);
        float4 bv = make_float4(0.f, 0.f, 0.f, 0.f);
        if (bvalid) bv = *(const float4*)(B + (size_t)rowB * ldb + k0 + lk);
        __syncthreads();
        As[lk+0][lr] = av.x; As[lk+1][lr] = av.y; As[lk+2][lr] = av.z; As[lk+3][lr] = av.w;
        Bs[lk+0][lr] = bv.x; Bs[lk+1][lr] = bv.y; Bs[lk+2][lr] = bv.z; Bs[lk+3][lr] = bv.w;
        __syncthreads();
        #pragma unroll
        for (int kk = 0; kk < 16; kk++) {
            float4 a = *(const float4*)&As[kk][ty*4];
            float4 b = *(const float4*)&Bs[kk][tx*4];
            acc[0][0] += a.x*b.x; acc[0][1] += a.x*b.y; acc[0][2] += a.x*b.z; acc[0][3] += a.x*b.w;
            acc[1][0] += a.y*b.x; acc[1][1] += a.y*b.y; acc[1][2] += a.y*b.z; acc[1][3] += a.y*b.w;
            acc[2][0] += a.z*b.x; acc[2][1] += a.z*b.y; acc[2][2] += a.z*b.z; acc[2][3] += a.z*b.w;
            acc[3][0] += a.w*b.x; acc[3][1] += a.w*b.y; acc[3][2] += a.w*b.z; acc[3][3] += a.w*b.w;
        }
    }

    const int col0 = bn + tx*4;
    #pragma unroll
    for (int i = 0; i < 4; i++) {
        int row = bm + ty*4 + i;
        float* crow = C + (size_t)row * ldc + col0;
        if (EPI == 1) {
            #pragma unroll
            for (int j = 0; j < 4; j++) {
                if (col0 + j < N) {
                    float v = acc[i][j] + bias[col0 + j];
                    v = fmaxf(v, 0.f) + log1pf(__expf(-fabsf(v)));  // stable softplus
                    crow[j] = v;
                }
            }
        } else {
            if (col0 + 4 <= N && (ldc & 3) == 0) {
                *(float4*)crow = make_float4(acc[i][0], acc[i][1], acc[i][2], acc[i][3]);
            } else {
                #pragma unroll
                for (int j = 0; j < 4; j++)
                    if (col0 + j < N) crow[j] = acc[i][j];
            }
        }
    }
}

// ---------------- causal depthwise conv (k=4) + bias + silu ----------------
__global__ void k_conv_silu(const float* __restrict__ xz, const float* __restrict__ cw,
                            const float* __restrict__ cb, float* __restrict__ xc) {
    int idx = blockIdx.x * 256 + threadIdx.x;
    if (idx >= NTOK * D_INNER) return;
    int d  = idx % D_INNER;
    int bt = idx / D_INNER;
    int t  = bt % NL;
    const float* xcol = xz + (size_t)bt * (2*D_INNER) + d;
    float4 w = *(const float4*)(cw + d*4);
    float acc = cb[d];
    if (t >= 3) {
        acc += xcol[-(ptrdiff_t)3*(2*D_INNER)] * w.x
             + xcol[-(ptrdiff_t)2*(2*D_INNER)] * w.y
             + xcol[-(ptrdiff_t)1*(2*D_INNER)] * w.z
             + xcol[0] * w.w;
    } else {
        const float* wf = (const float*)&w;
        for (int k = 0; k < 4; k++) {
            int tt = t - 3 + k;
            if (tt >= 0) acc += xz[((size_t)(bt - t + tt)) * (2*D_INNER) + d] * wf[k];
        }
    }
    xc[idx] = acc / (1.f + __expf(-acc));   // silu
}

// ---------------- chunked selective scan ----------------
// pass A: per (b,chunk,d): local scan from h=0; store h_end and P=prod(dA)
__global__ void k_scan_partial(const float* __restrict__ dt, const float* __restrict__ dbc,
                               const float* __restrict__ xc, const float* __restrict__ A_log,
                               float* __restrict__ chunk_h, float* __restrict__ chunk_P) {
    int gid = blockIdx.x * 256 + threadIdx.x;
    if (gid >= NB * CH * D_INNER) return;
    int d = gid % D_INNER;
    int c = (gid / D_INNER) % CH;
    int b = gid / (D_INNER * CH);
    float a[D_STATE], h[D_STATE], p[D_STATE];
    #pragma unroll
    for (int n = 0; n < D_STATE; n++) {
        a[n] = -expf(A_log[d*D_STATE + n]);
        h[n] = 0.f; p[n] = 1.f;
    }
    const int t0 = c * CHL;
    const float* dtp = dt + ((size_t)b*NL + t0)*D_INNER + d;
    const float* xcp = xc + ((size_t)b*NL + t0)*D_INNER + d;
    const float* bcp = dbc + ((size_t)b*NL + t0)*XPROJ_OUT + DT_RANK;
    for (int t = 0; t < CHL; t++) {
        float dtv = dtp[(size_t)t*D_INNER];
        float xv  = xcp[(size_t)t*D_INNER];
        const float* bc = bcp + (size_t)t*XPROJ_OUT;
        float4 B0 = *(const float4*)(bc + 0);
        float4 B1 = *(const float4*)(bc + 4);
        float4 B2 = *(const float4*)(bc + 8);
        float4 B3 = *(const float4*)(bc + 12);
        float Bv[16] = {B0.x,B0.y,B0.z,B0.w, B1.x,B1.y,B1.z,B1.w,
                        B2.x,B2.y,B2.z,B2.w, B3.x,B3.y,B3.z,B3.w};
        float dx = dtv * xv;
        #pragma unroll
        for (int n = 0; n < D_STATE; n++) {
            float dA = expf(dtv * a[n]);   // precise exp: error compounds over scan
            h[n] = dA * h[n] + dx * Bv[n];
            p[n] *= dA;
        }
    }
    size_t off = ((size_t)(b*CH + c)*D_INNER + d) * D_STATE;
    #pragma unroll
    for (int n = 0; n < D_STATE; n++) {
        chunk_h[off + n] = h[n];
        chunk_P[off + n] = p[n];
    }
}

// pass B: per (b,d): prefix-combine; chunk_h[c] becomes H_start for chunk c
__global__ void k_scan_combine(float* __restrict__ chunk_h, const float* __restrict__ chunk_P) {
    int gid = blockIdx.x * 256 + threadIdx.x;
    if (gid >= NB * D_INNER) return;
    int d = gid % D_INNER;
    int b = gid / D_INNER;
    float H[D_STATE];
    #pragma unroll
    for (int n = 0; n < D_STATE; n++) H[n] = 0.f;
    for (int c = 0; c < CH; c++) {
        size_t off = ((size_t)(b*CH + c)*D_INNER + d) * D_STATE;
        #pragma unroll
        for (int n = 0; n < D_STATE; n++) {
            float he = chunk_h[off + n];
            float P  = chunk_P[off + n];
            chunk_h[off + n] = H[n];          // H_start for chunk c
            H[n] = P * H[n] + he;
        }
    }
}

// pass C: per (b,chunk,d): re-scan from H_start, write gated output
__global__ void k_scan_final(const float* __restrict__ dt, const float* __restrict__ dbc,
                             const float* __restrict__ xc, const float* __restrict__ xz,
                             const float* __restrict__ A_log, const float* __restrict__ Dp,
                             const float* __restrict__ chunk_h, float* __restrict__ y) {
    int gid = blockIdx.x * 256 + threadIdx.x;
    if (gid >= NB * CH * D_INNER) return;
    int d = gid % D_INNER;
    int c = (gid / D_INNER) % CH;
    int b = gid / (D_INNER * CH);
    float a[D_STATE], h[D_STATE];
    size_t off = ((size_t)(b*CH + c)*D_INNER + d) * D_STATE;
    #pragma unroll
    for (int n = 0; n < D_STATE; n++) {
        a[n] = -expf(A_log[d*D_STATE + n]);
        h[n] = chunk_h[off + n];
    }
    float Dpd = Dp[d];
    const int t0 = c * CHL;
    const float* dtp = dt + ((size_t)b*NL + t0)*D_INNER + d;
    const float* xcp = xc + ((size_t)b*NL + t0)*D_INNER + d;
    const float* zp  = xz + ((size_t)b*NL + t0)*2*D_INNER + D_INNER + d;
    const float* bcp = dbc + ((size_t)b*NL + t0)*XPROJ_OUT + DT_RANK;
    float* yp = y + ((size_t)b*NL + t0)*D_INNER + d;
    for (int t = 0; t < CHL; t++) {
        float dtv = dtp[(size_t)t*D_INNER];
        float xv  = xcp[(size_t)t*D_INNER];
        float zv  = zp[(size_t)t*2*D_INNER];
        const float* bc = bcp + (size_t)t*XPROJ_OUT;
        float4 B0 = *(const float4*)(bc + 0);
        float4 B1 = *(const float4*)(bc + 4);
        float4 B2 = *(const float4*)(bc + 8);
        float4 B3 = *(const float4*)(bc + 12);
        float4 C0 = *(const float4*)(bc + 16);
        float4 C1 = *(const float4*)(bc + 20);
        float4 C2 = *(const float4*)(bc + 24);
        float4 C3 = *(const float4*)(bc + 28);
        float Bv[16] = {B0.x,B0.y,B0.z,B0.w, B1.x,B1.y,B1.z,B1.w,
                        B2.x,B2.y,B2.z,B2.w, B3.x,B3.y,B3.z,B3.w};
        float Cv[16] = {C0.x,C0.y,C0.z,C0.w, C1.x,C1.y,C1.z,C1.w,
                        C2.x,C2.y,C2.z,C2.w, C3.x,C3.y,C3.z,C3.w};
        float dx = dtv * xv;
        float acc = 0.f;
        #pragma unroll
        for (int n = 0; n < D_STATE; n++) {
            float dA = expf(dtv * a[n]);   // precise exp: error compounds over scan
            h[n] = dA * h[n] + dx * Bv[n];
            acc += h[n] * Cv[n];
        }
        float yv = acc + Dpd * xv;
        yv *= zv / (1.f + __expf(-zv));   // * silu(z)
        yp[(size_t)t*D_INNER] = yv;
    }
}

// ---------------- monolithic scan (fallback) ----------------
__global__ void k_scan(const float* __restrict__ dt, const float* __restrict__ dbc,
                       const float* __restrict__ xc, const float* __restrict__ xz,
                       const float* __restrict__ A_log, const float* __restrict__ Dp,
                       float* __restrict__ y) {
    int gid = blockIdx.x * blockDim.x + threadIdx.x;
    if (gid >= NB * D_INNER) return;
    int b = gid / D_INNER;
    int d = gid % D_INNER;
    float a[D_STATE], h[D_STATE];
    #pragma unroll
    for (int n = 0; n < D_STATE; n++) {
        a[n] = -expf(A_log[d*D_STATE + n]);
        h[n] = 0.f;
    }
    float Dpd = Dp[d];
    const float* dtp = dt + (size_t)b*NL*D_INNER + d;
    const float* xcp = xc + (size_t)b*NL*D_INNER + d;
    const float* zp  = xz + (size_t)b*NL*2*D_INNER + D_INNER + d;
    const float* bcp = dbc + (size_t)b*NL*XPROJ_OUT + DT_RANK;
    float* yp = y + (size_t)b*NL*D_INNER + d;
    for (int t = 0; t < NL; t++) {
        float dtv = dtp[(size_t)t*D_INNER];
        float xv  = xcp[(size_t)t*D_INNER];
        float zv  = zp[(size_t)t*2*D_INNER];
        const float* bc = bcp + (size_t)t*XPROJ_OUT;
        float4 B0 = *(const float4*)(bc + 0);
        float4 B1 = *(const float4*)(bc + 4);
        float4 B2 = *(const float4*)(bc + 8);
        float4 B3 = *(const float4*)(bc + 12);
        float4 C0 = *(const float4*)(bc + 16);
        float4 C1 = *(const float4*)(bc + 20);
        float4 C2 = *(const float4*)(bc + 24);
        float4 C3 = *(const float4*)(bc + 28);
        float Bv[16] = {B0.x,B0.y,B0.z,B0.w, B1.x,B1.y,B1.z,B1.w,
                        B2.x,B2.y,B2.z,B2.w, B3.x,B3.y,B3.z,B3.w};
        float Cv[16] = {C0.x,C0.y,C0.z,C0.w, C1.x,C1.y,C1.z,C1.w,
                        C2.x,C2.y,C2.z,C2.w, C3.x,C3.y,C3.z,C3.w};
        float dx = dtv * xv;
        float acc = 0.f;
        #pragma unroll
        for (int n = 0; n < D_STATE; n++) {
            float dA = expf(dtv * a[n]);
            h[n] = dA * h[n] + dx * Bv[n];
            acc += h[n] * Cv[n];
        }
        float yv = acc + Dpd * xv;
        yv *= zv / (1.f + __expf(-zv));
        yp[(size_t)t*D_INNER] = yv;
    }
}

// ---------------- layernorm over D_MODEL ----------------
__global__ void k_layernorm(const float* __restrict__ x, const float* __restrict__ w,
                            const float* __restrict__ bsr, float* __restrict__ out) {
    int row = blockIdx.x;
    const float* xr = x + (size_t)row * D_MODEL;
    float s = 0.f, s2 = 0.f;
    for (int i = threadIdx.x; i < D_MODEL; i += 256) {
        float v = xr[i];
        s += v; s2 += v*v;
    }
    #pragma unroll
    for (int off = 32; off; off >>= 1) {
        s  += __shfl_down(s, off);
        s2 += __shfl_down(s2, off);
    }
    __shared__ float red[2][4];
    int wv = threadIdx.x >> 6;
    if ((threadIdx.x & 63) == 0) { red[0][wv] = s; red[1][wv] = s2; }
    __syncthreads();
    float S  = red[0][0] + red[0][1] + red[0][2] + red[0][3];
    float S2 = red[1][0] + red[1][1] + red[1][2] + red[1][3];
    float mu  = S * (1.f/D_MODEL);
    float var = S2 * (1.f/D_MODEL) - mu*mu;
    float rstd = rsqrtf(var + 1e-5f);
    for (int i = threadIdx.x; i < D_MODEL; i += 256) {
        out[(size_t)row*D_MODEL + i] = (xr[i] - mu) * rstd * w[i] + bsr[i];
    }
}

// ---------------- launch ----------------
static inline void launch_split(const float* src, unsigned short* hi, unsigned short* lo,
                                size_t n, hipStream_t stream) {
    int n8 = (int)(n / 8);
    k_split<<<(n8 + 255)/256, 256, 0, stream>>>(src, hi, lo, n8);
}

extern "C" void kernel_launch(void* const* d_in, const int* in_sizes, int n_in,
                              void* d_out, int out_size, void* d_ws, size_t ws_size,
                              hipStream_t stream) {
    const int*   ids      = (const int*)  d_in[0];
    const float* emb      = (const float*)d_in[1];
    const float* in_proj  = (const float*)d_in[2];
    const float* conv_w   = (const float*)d_in[3];
    const float* conv_b   = (const float*)d_in[4];
    const float* x_proj   = (const float*)d_in[5];
    const float* dt_proj  = (const float*)d_in[6];
    const float* dt_bias  = (const float*)d_in[7];
    const float* A_log    = (const float*)d_in[8];
    const float* Dp       = (const float*)d_in[9];
    const float* out_proj = (const float*)d_in[10];
    const float* norm_w   = (const float*)d_in[11];
    const float* norm_b   = (const float*)d_in[12];
    const float* head_w   = (const float*)d_in[13];

    // fp32 workspace layout
    const size_t n_x   = (size_t)NTOK*D_MODEL;          // 1,572,864
    const size_t n_xz  = (size_t)NTOK*2*D_INNER;        // 6,291,456
    const size_t n_xc  = (size_t)NTOK*D_INNER;          // 3,145,728
    const size_t n_dbc = (size_t)NTOK*XPROJ_OUT;        //   163,840
    const size_t n_ck  = (size_t)NB*CH*D_INNER*D_STATE; //   786,432

    float* ws  = (float*)d_ws;
    float* x   = ws;
    float* xz  = x   + n_x;
    float* xc  = xz  + n_xz;
    float* dtb = xc  + n_xc;
    float* dbc = dtb + n_xc;
    float* y   = dbc + n_dbc;
    float* xn  = y   + n_xc;
    float* chh = xn  + n_x;          // chunk_h
    float* chp = chh + n_ck;         // chunk_P

    // split buffers: A (activations) sized for largest A (xc/y), W sized for
    // one head chunk (HCHK x D_MODEL) which also covers Wi (3072x768) and Wo.
    const size_t maxA  = n_xc;                          // 3,145,728 el
    const size_t nWBUF = (size_t)HCHK * D_MODEL;        // 9,830,400 el
    unsigned short* sAh = (unsigned short*)(chp + n_ck);
    unsigned short* sAl = sAh + maxA;
    unsigned short* sWh = sAl + maxA;
    unsigned short* sWl = sWh + nWBUF;
    const size_t req_full = (const char*)(sWl + nWBUF) - (const char*)d_ws;  // ~134 MB
    const size_t req_scan = (const char*)(chp + n_ck) - (const char*)d_ws;   // ~82 MB
    const bool full_path  = ws_size >= req_full;
    const bool chunk_scan = ws_size >= req_scan;

    k_embed<<<NTOK, 192, 0, stream>>>(ids, emb, x);

    for (int i = 0; i < N_LAYER; i++) {
        const float* Wi  = in_proj  + (size_t)i * 2*D_INNER*D_MODEL;
        const float* cw  = conv_w   + (size_t)i * D_INNER*D_CONV;
        const float* cb  = conv_b   + (size_t)i * D_INNER;
        const float* Wx  = x_proj   + (size_t)i * XPROJ_OUT*D_INNER;
        const float* Wdt = dt_proj  + (size_t)i * D_INNER*DT_RANK;
        const float* bdt = dt_bias  + (size_t)i * D_INNER;
        const float* Al  = A_log    + (size_t)i * D_INNER*D_STATE;
        const float* Dpi = Dp       + (size_t)i * D_INNER;
        const float* Wo  = out_proj + (size_t)i * D_MODEL*D_INNER;

        // xz = x @ Wi^T : (2048, 3072), K=768
        if (full_path) {
            launch_split(x,  sAh, sAl, n_x, stream);
            launch_split(Wi, sWh, sWl, (size_t)2*D_INNER*D_MODEL, stream);
            dim3 g(NTOK/128, (2*D_INNER)/128);
            k_gemm_pair<<<g, 256, 0, stream>>>(sAh, sAl, sWh, sWl, xz,
                NTOK, 2*D_INNER, D_MODEL, 2*D_INNER);
        } else {
            dim3 g(NTOK/128, (2*D_INNER)/128);
            k_gemm_split<<<g, 256, 0, stream>>>(x, Wi, xz,
                NTOK, 2*D_INNER, D_MODEL, D_MODEL, D_MODEL, 2*D_INNER);
        }
        // conv + silu -> xc
        k_conv_silu<<<(NTOK*D_INNER + 255)/256, 256, 0, stream>>>(xz, cw, cb, xc);
        // dbc = xc @ Wx^T : (2048, 80), K=1536 — fp32 path
        {
            dim3 g(NTOK/64, (XPROJ_OUT + 63)/64);
            k_gemm_nt<0><<<g, 256, 0, stream>>>(xc, Wx, nullptr, dbc,
                NTOK, XPROJ_OUT, D_INNER, D_INNER, D_INNER, XPROJ_OUT);
        }
        // dt = softplus(dbc[:, :48] @ Wdt^T + bdt) : (2048, 1536), K=48 — fp32
        {
            dim3 g(NTOK/64, D_INNER/64);
            k_gemm_nt<1><<<g, 256, 0, stream>>>(dbc, Wdt, bdt, dtb,
                NTOK, D_INNER, DT_RANK, XPROJ_OUT, DT_RANK, D_INNER);
        }
        // selective scan + Dp + gate -> y
        if (chunk_scan) {
            k_scan_partial<<<(NB*CH*D_INNER)/256, 256, 0, stream>>>(dtb, dbc, xc, Al, chh, chp);
            k_scan_combine<<<(NB*D_INNER + 255)/256, 256, 0, stream>>>(chh, chp);
            k_scan_final<<<(NB*CH*D_INNER)/256, 256, 0, stream>>>(dtb, dbc, xc, xz, Al, Dpi, chh, y);
        } else {
            k_scan<<<(NB*D_INNER + 255)/256, 256, 0, stream>>>(dtb, dbc, xc, xz, Al, Dpi, y);
        }
        // x = y @ Wo^T : (2048, 768), K=1536
        if (full_path) {
            launch_split(y,  sAh, sAl, n_xc, stream);
            launch_split(Wo, sWh, sWl, (size_t)D_MODEL*D_INNER, stream);
            dim3 g(NTOK/128, D_MODEL/128);
            k_gemm_pair<<<g, 256, 0, stream>>>(sAh, sAl, sWh, sWl, x,
                NTOK, D_MODEL, D_INNER, D_MODEL);
        } else {
            dim3 g(NTOK/128, D_MODEL/128);
            k_gemm_split<<<g, 256, 0, stream>>>(y, Wo, x,
                NTOK, D_MODEL, D_INNER, D_INNER, D_INNER, D_MODEL);
        }
    }

    k_layernorm<<<NTOK, 256, 0, stream>>>(x, norm_w, norm_b, xn);

    // logits = xn @ head_w^T : (2048, 50257), K=768 — vocab-chunked
    if (full_path) {
        launch_split(xn, sAh, sAl, n_x, stream);
        for (int r0 = 0; r0 < VOCAB; r0 += HCHK) {
            int rows = VOCAB - r0 < HCHK ? VOCAB - r0 : HCHK;
            launch_split(head_w + (size_t)r0 * D_MODEL, sWh, sWl,
                         (size_t)rows * D_MODEL, stream);
            dim3 g(NTOK/128, (rows + 127)/128);
            k_gemm_pair<<<g, 256, 0, stream>>>(sAh, sAl, sWh, sWl,
                (float*)d_out + r0, NTOK, rows, D_MODEL, VOCAB);
        }
    } else {
        dim3 g(NTOK/128, (VOCAB + 127)/128);
        k_gemm_split<<<g, 256, 0, stream>>>(xn, head_w, (float*)d_out,
            NTOK, VOCAB, D_MODEL, D_MODEL, D_MODEL, VOCAB);
    }
}